// Round 11
// baseline (293.322 us; speedup 1.0000x reference)
//
#include <hip/hip_runtime.h>

#define TSTEPS 64
#define NI 8192
#define NO 8192
#define DECAY 0.9375f

typedef __attribute__((ext_vector_type(8))) short bf16x8;   // MFMA A/B frag (4 VGPR)
typedef __attribute__((ext_vector_type(4))) float f32x4;    // MFMA C/D frag

// ---------------------------------------------------------------------------
// Kernel 1: spikes -> row-major bf16 S[t][k] (1 MB) with in-block layout
// self-detection (r9/r10, passing). Also zeroes cnt[256] for the stream-K
// fixup (re-run every call => replay-safe after 0xAA poison).
// ---------------------------------------------------------------------------
__global__ __launch_bounds__(256) void convert_kernel(const void* sp,
                                                      unsigned short* __restrict__ Sbf,
                                                      int* __restrict__ cnt) {
    if (threadIdx.x == 0) cnt[blockIdx.x] = 0;           // 256 blocks == 256 counters
    __shared__ int any;
    if (threadIdx.x == 0) any = 0;
    __syncthreads();
    int local = 0;
    const unsigned int* win = (const unsigned int*)sp;   // first 4 KB, both layouts
    #pragma unroll
    for (int i = 0; i < 4; ++i) {
        unsigned int v = win[threadIdx.x * 4 + i];
        if (v & 0xFFFFFF00u) local = 1;
    }
    if (local) atomicOr(&any, 1);
    __syncthreads();
    const int f = any;                                   // 1 => uint8 layout

    const int gid = blockIdx.x * 256 + threadIdx.x;      // 0..65535
    const int t   = gid >> 10;
    const int k0  = (gid & 1023) * 8;
    unsigned h[8];
    #pragma unroll
    for (int e = 0; e < 8; ++e) {
        int gi = t * NI + k0 + e;
        bool b;
        if (f) b = ((const unsigned char*)sp)[gi] != 0;
        else   b = ((const int*)sp)[gi] != 0;
        h[e] = b ? 0x3F80u : 0u;                         // bf16(1.0) = 0x3F80
    }
    uint4 v;
    v.x = h[0] | (h[1] << 16);
    v.y = h[2] | (h[3] << 16);
    v.z = h[4] | (h[5] << 16);
    v.w = h[6] | (h[7] << 16);
    *(uint4*)(Sbf + (size_t)t * NI + k0) = v;
}

// ---------------------------------------------------------------------------
// Triple split (UNCHANGED, passing): w = hi + mid + lo, error <= 2^-22 |w|.
// ---------------------------------------------------------------------------
__device__ __forceinline__ void split3(const float4& x, const float4& y,
                                       bf16x8& hi, bf16x8& mid, bf16x8& lo) {
    float v[8] = {x.x, x.y, x.z, x.w, y.x, y.y, y.z, y.w};
    #pragma unroll
    for (int e = 0; e < 8; ++e) {
        unsigned b   = __float_as_uint(v[e]);
        unsigned hb  = b & 0xFFFF0000u;
        float    r1  = v[e] - __uint_as_float(hb);                // exact
        unsigned r1b = __float_as_uint(r1);
        unsigned mb  = r1b & 0xFFFF0000u;
        float    r2  = r1 - __uint_as_float(mb);                  // exact
        unsigned r2b = __float_as_uint(r2);
        unsigned lr  = (r2b + 0x7FFFu + ((r2b >> 16) & 1u)) >> 16; // RNE bf16
        hi[e]  = (short)(b >> 16);
        mid[e] = (short)(mb >> 16);
        lo[e]  = (short)lr;
    }
}

// ---------------------------------------------------------------------------
// Kernel 2: GEMM + in-block LDS K-reduce + stream-K tail (final reduce+scan).
// Per-wave geometry IDENTICAL to r5/r10 (proven best): 32o x 64t x 512k,
// 16 chunks of K=32, ~310 busy cyc/chunk, 4 blocks/CU = 16 waves/CU.
// New tiling: block = 32 o-rows; its 4 waves k-split a 2048-k span.
// Grid 1024 = 256 ob x 4 kb (kb-minor => siblings co-dispatch, tail starts
// early). Block LDS-reduces its 4 waves -> partial[ob][kb][t][o] (8 MB).
// Fixup: fence; barrier; tid0 atomicAdd(cnt[ob]); 4th arriver re-fences
// (acquire invalidates local L2 -> cross-XCD safe), sums kb=0..3 in fixed
// order (deterministic), scans 32 neurons in-LDS, writes out directly.
// No spinning => no deadlock under any dispatch order.
// ---------------------------------------------------------------------------
__global__ __launch_bounds__(256, 4) void gemm_kernel(const float* __restrict__ W,
                                                      const unsigned short* __restrict__ Sbf,
                                                      float* __restrict__ partial,
                                                      int* __restrict__ cnt,
                                                      float* __restrict__ out) {
    __shared__ float red[4][32][65];   // 33.3 KB: wave-acc staging + tail currents
    __shared__ int isLast;

    const int tid  = threadIdx.x;
    const int lane = tid & 63;
    const int w    = tid >> 6;
    const int ob   = blockIdx.x >> 2;   // 256 o-blocks of 32
    const int kb   = blockIdx.x & 3;    // 4 k-splits (kb-minor dispatch)
    const int r16  = lane & 15;
    const int kg   = lane >> 4;
    const int o0   = ob * 32;
    const int kbase = kb * 2048 + w * 512 + kg * 8;

    f32x4 acc[2][4];
    #pragma unroll
    for (int m = 0; m < 2; ++m)
        #pragma unroll
        for (int n = 0; n < 4; ++n) acc[m][n] = (f32x4)0.f;

    const float* ap[2];
    #pragma unroll
    for (int m = 0; m < 2; ++m)
        ap[m] = W + (size_t)(o0 + m * 16 + r16) * NI + kbase;
    const unsigned short* bp[4];
    #pragma unroll
    for (int n = 0; n < 4; ++n)
        bp[n] = Sbf + (size_t)(n * 16 + r16) * NI + kbase;

    #pragma unroll 4
    for (int c = 0; c < 16; ++c) {
        bf16x8 Bf[4];
        #pragma unroll
        for (int n = 0; n < 4; ++n)
            Bf[n] = *(const bf16x8*)(bp[n] + c * 32);
        #pragma unroll
        for (int m = 0; m < 2; ++m) {
            float4 a0 = *(const float4*)(ap[m] + c * 32);
            float4 a1 = *(const float4*)(ap[m] + c * 32 + 4);
            bf16x8 hi, mid, lo;
            split3(a0, a1, hi, mid, lo);
            #pragma unroll
            for (int n = 0; n < 4; ++n) {
                acc[m][n] = __builtin_amdgcn_mfma_f32_16x16x32_bf16(
                    hi, Bf[n], acc[m][n], 0, 0, 0);
                acc[m][n] = __builtin_amdgcn_mfma_f32_16x16x32_bf16(
                    mid, Bf[n], acc[m][n], 0, 0, 0);
                acc[m][n] = __builtin_amdgcn_mfma_f32_16x16x32_bf16(
                    lo, Bf[n], acc[m][n], 0, 0, 0);
            }
        }
    }

    // acc -> LDS per verified D-map: o = m*16 + kg*4 + reg, t = n*16 + r16.
    #pragma unroll
    for (int m = 0; m < 2; ++m)
        #pragma unroll
        for (int n = 0; n < 4; ++n)
            #pragma unroll
            for (int r = 0; r < 4; ++r)
                red[w][m * 16 + kg * 4 + r][n * 16 + r16] = acc[m][n][r];
    __syncthreads();

    // In-block deterministic 4-wave reduce -> partial slice (8 KB, coalesced).
    float* slice = partial + ((size_t)(ob * 4 + kb)) * 2048;
    #pragma unroll
    for (int j = 0; j < 8; ++j) {
        int cell = j * 256 + tid;
        int o = cell & 31, t = cell >> 5;
        float s = red[0][o][t] + red[1][o][t] + red[2][o][t] + red[3][o][t];
        slice[t * 32 + o] = s;
    }

    // Release: make this block's partial writes device-visible, then count in.
    __threadfence();
    __syncthreads();
    if (tid == 0)
        isLast = (atomicAdd(&cnt[ob], 1) == 3);
    __syncthreads();
    if (!isLast) return;

    // Acquire: invalidate local caches so sibling slices read fresh.
    __threadfence();

    // Tail: deterministic kb-order sum of the 4 slices -> red[0] (currents).
    const float* pb = partial + ((size_t)(ob * 4)) * 2048;
    #pragma unroll
    for (int j = 0; j < 8; ++j) {
        int cell = j * 256 + tid;
        int o = cell & 31, t = cell >> 5;
        float s = pb[t * 32 + o] + pb[2048 + t * 32 + o]
                + pb[4096 + t * 32 + o] + pb[6144 + t * 32 + o];
        red[0][o][t] = s;
    }
    __syncthreads();

    // LIF scan for this block's 32 neurons (threads 0..31, conflict-free LDS).
    if (tid < 32) {
        const int o = tid;
        float m = 0.f;
        out[o0 + o] = 0.f;                               // spike row 0
        #pragma unroll 4
        for (int t = 0; t < TSTEPS; ++t) {
            m += red[0][o][t];
            bool sp = (m >= 1.0f);
            out[(size_t)(t + 1) * NO + o0 + o] = sp ? 1.0f : 0.0f;
            m = sp ? (m - 1.0f) : m * DECAY;
        }
        out[(size_t)(TSTEPS + 1) * NO + o0 + o] = m;     // final mempot
    }
}

// ---------------------------------------------------------------------------
extern "C" void kernel_launch(void* const* d_in, const int* in_sizes, int n_in,
                              void* d_out, int out_size, void* d_ws, size_t ws_size,
                              hipStream_t stream) {
    const void*  spikes = d_in[0];
    const float* W      = (const float*)d_in[1];
    float*       out    = (float*)d_out;
    char*        ws     = (char*)d_ws;

    // ws layout: [Sbf 1 MB][cnt 1 KB (pad to 4 KB)][partial 8 MB] ~= 9 MB
    unsigned short* Sbf     = (unsigned short*)ws;
    int*            cnt     = (int*)(ws + (size_t)1048576);
    float*          partial = (float*)(ws + (size_t)1048576 + 4096);

    hipLaunchKernelGGL(convert_kernel, dim3(256),  dim3(256), 0, stream,
                       spikes, Sbf, cnt);
    hipLaunchKernelGGL(gemm_kernel,    dim3(1024), dim3(256), 0, stream,
                       W, Sbf, partial, cnt, out);
}

// Round 12
// 132.728 us; speedup vs baseline: 2.2099x; 2.2099x over previous
//
#include <hip/hip_runtime.h>

#define TSTEPS 64
#define NI 8192
#define NO 8192
#define KS 16                 // K-split factor
#define KCH (NI / KS)         // 512 k per block
#define NC (KCH / 32)         // 16 K=32 chunks per wave
#define DECAY 0.9375f

typedef __attribute__((ext_vector_type(8))) short bf16x8;   // MFMA A/B frag (4 VGPR)
typedef __attribute__((ext_vector_type(4))) float f32x4;    // MFMA C/D frag

// ---------------------------------------------------------------------------
// Kernel 1 (verbatim r10, passing): spikes -> row-major bf16 S[t][k] (1 MB)
// with in-block layout self-detection on the shared first-4KB window.
// ---------------------------------------------------------------------------
__global__ __launch_bounds__(256) void convert_kernel(const void* sp,
                                                      unsigned short* __restrict__ Sbf) {
    __shared__ int any;
    if (threadIdx.x == 0) any = 0;
    __syncthreads();
    int local = 0;
    const unsigned int* win = (const unsigned int*)sp;   // first 4 KB, both layouts
    #pragma unroll
    for (int i = 0; i < 4; ++i) {
        unsigned int v = win[threadIdx.x * 4 + i];
        if (v & 0xFFFFFF00u) local = 1;
    }
    if (local) atomicOr(&any, 1);
    __syncthreads();
    const int f = any;                                   // 1 => uint8 layout

    const int gid = blockIdx.x * 256 + threadIdx.x;      // 0..65535
    const int t   = gid >> 10;
    const int k0  = (gid & 1023) * 8;
    unsigned h[8];
    #pragma unroll
    for (int e = 0; e < 8; ++e) {
        int gi = t * NI + k0 + e;
        bool b;
        if (f) b = ((const unsigned char*)sp)[gi] != 0;
        else   b = ((const int*)sp)[gi] != 0;
        h[e] = b ? 0x3F80u : 0u;                         // bf16(1.0) = 0x3F80
    }
    uint4 v;
    v.x = h[0] | (h[1] << 16);
    v.y = h[2] | (h[3] << 16);
    v.z = h[4] | (h[5] << 16);
    v.w = h[6] | (h[7] << 16);
    *(uint4*)(Sbf + (size_t)t * NI + k0) = v;
}

// ---------------------------------------------------------------------------
// Triple split (UNCHANGED, passing): w = hi + mid + lo, error <= 2^-22 |w|.
// ---------------------------------------------------------------------------
__device__ __forceinline__ void split3(const float4& x, const float4& y,
                                       bf16x8& hi, bf16x8& mid, bf16x8& lo) {
    float v[8] = {x.x, x.y, x.z, x.w, y.x, y.y, y.z, y.w};
    #pragma unroll
    for (int e = 0; e < 8; ++e) {
        unsigned b   = __float_as_uint(v[e]);
        unsigned hb  = b & 0xFFFF0000u;
        float    r1  = v[e] - __uint_as_float(hb);                // exact
        unsigned r1b = __float_as_uint(r1);
        unsigned mb  = r1b & 0xFFFF0000u;
        float    r2  = r1 - __uint_as_float(mb);                  // exact
        unsigned r2b = __float_as_uint(r2);
        unsigned lr  = (r2b + 0x7FFFu + ((r2b >> 16) & 1u)) >> 16; // RNE bf16
        hi[e]  = (short)(b >> 16);
        mid[e] = (short)(mb >> 16);
        lo[e]  = (short)lr;
    }
}

// ---------------------------------------------------------------------------
// Kernel 2: skinny GEMM via triple-split bf16 MFMA — occupancy-doubled.
// Per-wave tile 16o x 64t x 512k (acc 16 + B 16 + A/split ~20 + addr ~12
// ~= 60 VGPR), __launch_bounds__(256, 8) -> 8 waves/SIMD, grid 128 ob x
// 16 kb = 2048 blocks = 8 blocks/CU = 32 waves/CU. Little's law: ~256 B
// in flight per wave x 32 waves ~= 8 KB/CU ~= latency-BW product -> BW-
// limited instead of latency-limited. No LDS, no barriers, no fences.
// partial[kb][t][o] = sum_{k in chunk kb} W[o][k] * S[k][t]
// ---------------------------------------------------------------------------
__global__ __launch_bounds__(256, 8) void gemm_kernel(const float* __restrict__ W,
                                                      const unsigned short* __restrict__ Sbf,
                                                      float* __restrict__ partial) {
    const int lane = threadIdx.x & 63;
    const int w    = threadIdx.x >> 6;
    const int ob   = blockIdx.x & 127;  // 128 o-blocks of 64 rows
    const int kb   = blockIdx.x >> 7;   // 16 k-splits
    const int r16  = lane & 15;
    const int kg   = lane >> 4;
    const int o0   = ob * 64 + w * 16;
    const int kbase = kb * KCH + kg * 8;

    f32x4 acc[4];
    #pragma unroll
    for (int n = 0; n < 4; ++n) acc[n] = (f32x4)0.f;

    const float* ap = W + (size_t)(o0 + r16) * NI + kbase;
    const unsigned short* bp[4];
    #pragma unroll
    for (int n = 0; n < 4; ++n)
        bp[n] = Sbf + (size_t)(n * 16 + r16) * NI + kbase;

    #pragma unroll 4
    for (int c = 0; c < NC; ++c) {
        bf16x8 Bf[4];
        #pragma unroll
        for (int n = 0; n < 4; ++n)
            Bf[n] = *(const bf16x8*)(bp[n] + c * 32);
        float4 a0 = *(const float4*)(ap + c * 32);
        float4 a1 = *(const float4*)(ap + c * 32 + 4);
        bf16x8 hi, mid, lo;
        split3(a0, a1, hi, mid, lo);
        #pragma unroll
        for (int n = 0; n < 4; ++n) {
            acc[n] = __builtin_amdgcn_mfma_f32_16x16x32_bf16(hi,  Bf[n], acc[n], 0, 0, 0);
            acc[n] = __builtin_amdgcn_mfma_f32_16x16x32_bf16(mid, Bf[n], acc[n], 0, 0, 0);
            acc[n] = __builtin_amdgcn_mfma_f32_16x16x32_bf16(lo,  Bf[n], acc[n], 0, 0, 0);
        }
    }

    // Epilogue per verified D-map: t(col) = n*16 + r16, o(row) = 4*kg + reg.
    #pragma unroll
    for (int n = 0; n < 4; ++n) {
        int t = n * 16 + r16;
        size_t off = (size_t)kb * TSTEPS * NO + (size_t)t * NO + (o0 + kg * 4);
        *(f32x4*)&partial[off] = acc[n];
    }
}

// ---------------------------------------------------------------------------
// Kernel 3 (verbatim r10, passing): deterministic K-split reduction.
// Full-grid (2048 blocks) so the 32 MB partial read gets chip-wide BW.
// ---------------------------------------------------------------------------
__global__ __launch_bounds__(256) void reduce_kernel(const float* __restrict__ partial,
                                                     float* __restrict__ currents) {
    int gid = blockIdx.x * 256 + threadIdx.x;   // over 64*8192
    float s = 0.f;
    #pragma unroll
    for (int kb = 0; kb < KS; ++kb) s += partial[(size_t)kb * TSTEPS * NO + gid];
    currents[gid] = s;
}

// ---------------------------------------------------------------------------
// Kernel 4 (verbatim r10, passing): per-neuron LIF scan.
// out = [spikes(65 x 8192) as f32 0/1, final mempot(8192)]
// ---------------------------------------------------------------------------
__global__ __launch_bounds__(256) void scan_kernel(const float* __restrict__ currents,
                                                   float* __restrict__ out) {
    int o = blockIdx.x * 256 + threadIdx.x;
    float m = 0.f;
    out[o] = 0.f;                                // spike row 0 stays zero
    for (int t = 0; t < TSTEPS; ++t) {
        m += currents[t * NO + o];
        bool sp = (m >= 1.0f);
        out[(size_t)(t + 1) * NO + o] = sp ? 1.0f : 0.0f;
        m = sp ? (m - 1.0f) : m * DECAY;
    }
    out[(size_t)(TSTEPS + 1) * NO + o] = m;      // final mempot
}

// ---------------------------------------------------------------------------
extern "C" void kernel_launch(void* const* d_in, const int* in_sizes, int n_in,
                              void* d_out, int out_size, void* d_ws, size_t ws_size,
                              hipStream_t stream) {
    const void*  spikes = d_in[0];
    const float* W      = (const float*)d_in[1];
    float*       out    = (float*)d_out;
    char*        ws     = (char*)d_ws;

    // ws layout: [Sbf 1 MB][partial 32 MB][currents 2 MB] ~= 35 MB
    unsigned short* Sbf      = (unsigned short*)ws;
    float*          partial  = (float*)(ws + (size_t)1048576);
    float*          currents = (float*)(ws + (size_t)1048576
                                           + (size_t)KS * TSTEPS * NO * 4);

    hipLaunchKernelGGL(convert_kernel, dim3(256),               dim3(256), 0, stream,
                       spikes, Sbf);
    hipLaunchKernelGGL(gemm_kernel,    dim3(128 * KS),          dim3(256), 0, stream,
                       W, Sbf, partial);
    hipLaunchKernelGGL(reduce_kernel,  dim3(TSTEPS * NO / 256), dim3(256), 0, stream,
                       partial, currents);
    hipLaunchKernelGGL(scan_kernel,    dim3(NO / 256),          dim3(256), 0, stream,
                       currents, out);
}

// Round 13
// 97.428 us; speedup vs baseline: 3.0106x; 1.3623x over previous
//
#include <hip/hip_runtime.h>

#define TSTEPS 64
#define NI 8192
#define NO 8192
#define KS 16                 // K-split factor
#define KCH (NI / KS)         // 512 k per block
#define DECAY 0.9375f

typedef __attribute__((ext_vector_type(8))) short bf16x8;   // MFMA A/B frag (4 VGPR)
typedef __attribute__((ext_vector_type(4))) float f32x4;    // MFMA C/D frag

// ---------------------------------------------------------------------------
// Kernel 1 (verbatim r10, passing): spikes -> row-major bf16 S[t][k] (1 MB)
// with in-block layout self-detection on the shared first-4KB window.
// ---------------------------------------------------------------------------
__global__ __launch_bounds__(256) void convert_kernel(const void* sp,
                                                      unsigned short* __restrict__ Sbf) {
    __shared__ int any;
    if (threadIdx.x == 0) any = 0;
    __syncthreads();
    int local = 0;
    const unsigned int* win = (const unsigned int*)sp;   // first 4 KB, both layouts
    #pragma unroll
    for (int i = 0; i < 4; ++i) {
        unsigned int v = win[threadIdx.x * 4 + i];
        if (v & 0xFFFFFF00u) local = 1;
    }
    if (local) atomicOr(&any, 1);
    __syncthreads();
    const int f = any;                                   // 1 => uint8 layout

    const int gid = blockIdx.x * 256 + threadIdx.x;      // 0..65535
    const int t   = gid >> 10;
    const int k0  = (gid & 1023) * 8;
    unsigned h[8];
    #pragma unroll
    for (int e = 0; e < 8; ++e) {
        int gi = t * NI + k0 + e;
        bool b;
        if (f) b = ((const unsigned char*)sp)[gi] != 0;
        else   b = ((const int*)sp)[gi] != 0;
        h[e] = b ? 0x3F80u : 0u;                         // bf16(1.0) = 0x3F80
    }
    uint4 v;
    v.x = h[0] | (h[1] << 16);
    v.y = h[2] | (h[3] << 16);
    v.z = h[4] | (h[5] << 16);
    v.w = h[6] | (h[7] << 16);
    *(uint4*)(Sbf + (size_t)t * NI + k0) = v;
}

// ---------------------------------------------------------------------------
// Triple split (UNCHANGED, passing): w = hi + mid + lo, error <= 2^-22 |w|.
// ---------------------------------------------------------------------------
__device__ __forceinline__ void split3(const float4& x, const float4& y,
                                       bf16x8& hi, bf16x8& mid, bf16x8& lo) {
    float v[8] = {x.x, x.y, x.z, x.w, y.x, y.y, y.z, y.w};
    #pragma unroll
    for (int e = 0; e < 8; ++e) {
        unsigned b   = __float_as_uint(v[e]);
        unsigned hb  = b & 0xFFFF0000u;
        float    r1  = v[e] - __uint_as_float(hb);                // exact
        unsigned r1b = __float_as_uint(r1);
        unsigned mb  = r1b & 0xFFFF0000u;
        float    r2  = r1 - __uint_as_float(mb);                  // exact
        unsigned r2b = __float_as_uint(r2);
        unsigned lr  = (r2b + 0x7FFFu + ((r2b >> 16) & 1u)) >> 16; // RNE bf16
        hi[e]  = (short)(b >> 16);
        mid[e] = (short)(mb >> 16);
        lo[e]  = (short)lr;
    }
}

// ---------------------------------------------------------------------------
// Async global->LDS DMA, 16 B/lane: dst = wave-uniform base + lane*16;
// per-lane SOURCE address carries the swizzle (m173/r8-proven pattern).
// ---------------------------------------------------------------------------
__device__ __forceinline__ void gload_lds16(const float* g, float* l) {
    __builtin_amdgcn_global_load_lds(
        (const __attribute__((address_space(1))) void*)g,
        (__attribute__((address_space(3))) void*)l, 16, 0, 0);
}

#define MFMA_BF16 __builtin_amdgcn_mfma_f32_16x16x32_bf16
// Counted wait: one chunk's 8 ops (4 A-DMA + 4 B-loads) may stay in flight.
// sched_barrier stops MFMAs/ds_reads floating above the wait (rule #18).
#define WAIT8() do { asm volatile("s_waitcnt vmcnt(8)" ::: "memory"); \
                     __builtin_amdgcn_sched_barrier(0); } while (0)

// ---------------------------------------------------------------------------
// Kernel 2: skinny GEMM — r10-identical geometry (32o x 64t x 512k waves,
// 64 ob x 16 kb = 1024 blocks, 4/CU, 16 waves/CU), ONE change: the A-operand
// is staged through wave-private LDS via swizzled global_load_lds.
//  - DMA instr (m,j): lanes cover rows m*16+8j..+8 x 128 B contiguous
//    (fully-covered lines; fixes the 16-row x 16-B scatter of direct loads)
//  - source unit pre-XOR'd: slot u^(row&7) holds unit u -> ds_read phases
//    are 2-way max (free)
//  - double-buffered (2 stages x 4 KB/wave), no barriers (wave-private),
//    vmcnt(8) counted waits, never 0 in the loop
// partial[kb][t][o] = sum_{k in chunk kb} W[o][k] * S[k][t]
// ---------------------------------------------------------------------------
__global__ __launch_bounds__(256, 4) void gemm_kernel(const float* __restrict__ W,
                                                      const unsigned short* __restrict__ Sbf,
                                                      float* __restrict__ partial) {
    __shared__ __align__(1024) float lds[8192];   // 32 KB: 4 waves x 2 stages x 4 KB

    const int lane = threadIdx.x & 63;
    const int w    = threadIdx.x >> 6;
    const int ob   = blockIdx.x & 63;   // 64 o-blocks of 128 rows
    const int kb   = blockIdx.x >> 6;   // 16 k-splits
    const int r16  = lane & 15;
    const int kg   = lane >> 4;
    const int o0   = ob * 128 + w * 32;
    const int kblk = kb * KCH;

    char* wlds = (char*)lds + w * 8192;  // wave-private 2-stage region

    // DMA source pointers: instr (m,j) covers rows m*16+8j+(lane>>3),
    // source unit (lane&7)^(row&7)  [row&7 == (lane>>3)&7].
    const float* gw[2][2];
    #pragma unroll
    for (int m = 0; m < 2; ++m)
        #pragma unroll
        for (int j = 0; j < 2; ++j) {
            int row  = m * 16 + j * 8 + (lane >> 3);
            int usrc = (lane & 7) ^ ((lane >> 3) & 7);
            gw[m][j] = W + (size_t)(o0 + row) * NI + kblk + usrc * 4;
        }

    // LDS read offsets: A half h (0=a0,1=a1) of m-tile at row r16 lives at
    // slot (kg*2+h)^(r16&7): byte = m*2048 + r16*128 + slot*16.
    int offA[2][2];
    #pragma unroll
    for (int m = 0; m < 2; ++m)
        #pragma unroll
        for (int h = 0; h < 2; ++h)
            offA[m][h] = m * 2048 + r16 * 128 + (((kg * 2 + h) ^ (r16 & 7)) * 16);

    const unsigned short* bp[4];
    #pragma unroll
    for (int n = 0; n < 4; ++n)
        bp[n] = Sbf + (size_t)(n * 16 + r16) * NI + kblk + kg * 8;

    f32x4 acc[2][4];
    #pragma unroll
    for (int m = 0; m < 2; ++m)
        #pragma unroll
        for (int n = 0; n < 4; ++n) acc[m][n] = (f32x4)0.f;

    bf16x8 bX[4], bY[4];

    #define ISSUE_A(cc, stage) do {                                          \
        char* _d = wlds + (stage) * 4096;                                    \
        _Pragma("unroll") for (int m = 0; m < 2; ++m)                        \
        _Pragma("unroll") for (int j = 0; j < 2; ++j)                        \
            gload_lds16(gw[m][j] + (cc) * 32,                                \
                        (float*)(_d + m * 2048 + j * 1024));                 \
    } while (0)

    #define ISSUE_B(BB, cc) do {                                             \
        _Pragma("unroll") for (int n = 0; n < 4; ++n)                        \
            BB[n] = *(const bf16x8*)(bp[n] + (cc) * 32);                     \
    } while (0)

    #define COMPUTE(stage, BB) do {                                          \
        const char* _s = wlds + (stage) * 4096;                              \
        _Pragma("unroll") for (int m = 0; m < 2; ++m) {                      \
            float4 a0 = *(const float4*)(_s + offA[m][0]);                   \
            float4 a1 = *(const float4*)(_s + offA[m][1]);                   \
            bf16x8 hi, mid, lo;                                              \
            split3(a0, a1, hi, mid, lo);                                     \
            _Pragma("unroll") for (int n = 0; n < 4; ++n) {                  \
                acc[m][n] = MFMA_BF16(hi,  BB[n], acc[m][n], 0, 0, 0);       \
                acc[m][n] = MFMA_BF16(mid, BB[n], acc[m][n], 0, 0, 0);       \
                acc[m][n] = MFMA_BF16(lo,  BB[n], acc[m][n], 0, 0, 0);       \
            }                                                                \
        }                                                                    \
    } while (0)

    // Prologue: chunks 0,1 in flight (16 ops).
    ISSUE_A(0, 0); ISSUE_B(bX, 0);
    ISSUE_A(1, 1); ISSUE_B(bY, 1);

    #pragma unroll 1
    for (int c = 0; c < 16; c += 2) {
        WAIT8();                                   // chunk c landed
        COMPUTE(0, bX);
        ISSUE_A((c + 2) & 15, 0); ISSUE_B(bX, (c + 2) & 15);
        WAIT8();                                   // chunk c+1 landed
        COMPUTE(1, bY);
        ISSUE_A((c + 3) & 15, 1); ISSUE_B(bY, (c + 3) & 15);
    }
    // Tail prefetches wrap to chunks 0,1: in-bounds, unused.

    // Epilogue per verified D-map: t(col) = n*16 + r16, o(row) = 4*kg + reg.
    #pragma unroll
    for (int m = 0; m < 2; ++m)
        #pragma unroll
        for (int n = 0; n < 4; ++n) {
            int t = n * 16 + r16;
            size_t off = (size_t)kb * TSTEPS * NO + (size_t)t * NO
                       + (o0 + m * 16 + kg * 4);
            *(f32x4*)&partial[off] = acc[m][n];
        }
}

// ---------------------------------------------------------------------------
// Kernel 3 (verbatim r10, passing): deterministic K-split reduction.
// ---------------------------------------------------------------------------
__global__ __launch_bounds__(256) void reduce_kernel(const float* __restrict__ partial,
                                                     float* __restrict__ currents) {
    int gid = blockIdx.x * 256 + threadIdx.x;   // over 64*8192
    float s = 0.f;
    #pragma unroll
    for (int kb = 0; kb < KS; ++kb) s += partial[(size_t)kb * TSTEPS * NO + gid];
    currents[gid] = s;
}

// ---------------------------------------------------------------------------
// Kernel 4 (verbatim r10, passing): per-neuron LIF scan.
// out = [spikes(65 x 8192) as f32 0/1, final mempot(8192)]
// ---------------------------------------------------------------------------
__global__ __launch_bounds__(256) void scan_kernel(const float* __restrict__ currents,
                                                   float* __restrict__ out) {
    int o = blockIdx.x * 256 + threadIdx.x;
    float m = 0.f;
    out[o] = 0.f;                                // spike row 0 stays zero
    for (int t = 0; t < TSTEPS; ++t) {
        m += currents[t * NO + o];
        bool sp = (m >= 1.0f);
        out[(size_t)(t + 1) * NO + o] = sp ? 1.0f : 0.0f;
        m = sp ? (m - 1.0f) : m * DECAY;
    }
    out[(size_t)(TSTEPS + 1) * NO + o] = m;      // final mempot
}

// ---------------------------------------------------------------------------
extern "C" void kernel_launch(void* const* d_in, const int* in_sizes, int n_in,
                              void* d_out, int out_size, void* d_ws, size_t ws_size,
                              hipStream_t stream) {
    const void*  spikes = d_in[0];
    const float* W      = (const float*)d_in[1];
    float*       out    = (float*)d_out;
    char*        ws     = (char*)d_ws;

    // ws layout: [Sbf 1 MB][partial 32 MB][currents 2 MB] ~= 35 MB
    unsigned short* Sbf      = (unsigned short*)ws;
    float*          partial  = (float*)(ws + (size_t)1048576);
    float*          currents = (float*)(ws + (size_t)1048576
                                           + (size_t)KS * TSTEPS * NO * 4);

    hipLaunchKernelGGL(convert_kernel, dim3(256),               dim3(256), 0, stream,
                       spikes, Sbf);
    hipLaunchKernelGGL(gemm_kernel,    dim3(64 * KS),           dim3(256), 0, stream,
                       W, Sbf, partial);
    hipLaunchKernelGGL(reduce_kernel,  dim3(TSTEPS * NO / 256), dim3(256), 0, stream,
                       partial, currents);
    hipLaunchKernelGGL(scan_kernel,    dim3(NO / 256),          dim3(256), 0, stream,
                       currents, out);
}